// Round 6
// baseline (222.997 us; speedup 1.0000x reference)
//
#include <hip/hip_runtime.h>
#include <hip/hip_bf16.h>

#define Bq   4
#define Lq   9216
#define DIMc 256
#define NHc  8
#define NPc  4
#define HDc  32
#define SIDEc 96

using f32x4  = __attribute__((ext_vector_type(4))) float;
using bf16x8 = __attribute__((ext_vector_type(8))) short;
using u16x8  = __attribute__((ext_vector_type(8))) unsigned short;
using h16x4  = __attribute__((ext_vector_type(4))) _Float16;

static __device__ __forceinline__ short f2bf(float x) {
    union { __hip_bfloat16 h; short s; } u;
    u.h = __float2bfloat16(x);
    return u.s;
}
static __device__ __forceinline__ float bfbits(unsigned short s) {
    union { unsigned u; float f; } v; v.u = ((unsigned)s) << 16; return v.f;
}

// blocks 0..63: coalesced transpose Wv/Wo -> WT[n][k] bf16 (8 cols/block via LDS).
// blocks 64..159: split-bf16 projection weights WpHi/WpLo [96][256].
__global__ void prep(const float* __restrict__ Wv, const float* __restrict__ Wo,
                     const float* __restrict__ Woff, const float* __restrict__ Wwt,
                     short* __restrict__ WvT, short* __restrict__ WoT,
                     short* __restrict__ WpHi, short* __restrict__ WpLo) {
    const int id = blockIdx.x, t = threadIdx.x;
    if (id < 64) {
        __shared__ float tile[256][8];
        const float* W = (id < 32) ? Wv : Wo;
        short* T = (id < 32) ? WvT : WoT;
        const int n0 = (id & 31) * 8;
        const float4 a = *(const float4*)&W[t * 256 + n0];
        const float4 b = *(const float4*)&W[t * 256 + n0 + 4];
        tile[t][0] = a.x; tile[t][1] = a.y; tile[t][2] = a.z; tile[t][3] = a.w;
        tile[t][4] = b.x; tile[t][5] = b.y; tile[t][6] = b.z; tile[t][7] = b.w;
        __syncthreads();
        const int n = n0 + (t >> 5), kk = (t & 31) * 8;
        bf16x8 v;
#pragma unroll
        for (int e = 0; e < 8; ++e) v[e] = f2bf(tile[kk + e][t >> 5]);
        *(bf16x8*)&T[n * 256 + kk] = v;
    } else {
        const int p = id - 64;       // 0..95
        const float x = (p < 64) ? Woff[t * 64 + p] : Wwt[t * 32 + (p - 64)];
        const short h = f2bf(x);
        WpHi[p * 256 + t] = h;
        WpLo[p * 256 + t] = f2bf(x - bfbits((unsigned short)h));
    }
}

// gemm1 + fused Q-projection.  BM=32, 4 waves.
// value GEMM: wave w -> cols w*64..w*64+63, all 32 rows (acc 2x4), out bf16 [B,NH,L,HD].
// proj: wave w -> rows (w>>1)*16, cols (w&1)*48 (3 chains x 3 MFMA split-bf16),
//       A-frags straight from global Q (each Q row read by exactly one wave).
__global__ __launch_bounds__(256, 3) void gemm1_proj(
        const float* __restrict__ X, const float* __restrict__ Q,
        const short* __restrict__ WT,
        const short* __restrict__ WpHi, const short* __restrict__ WpLo,
        const float* __restrict__ bias,
        const float* __restrict__ boff, const float* __restrict__ bwt,
        __hip_bfloat16* __restrict__ Yv, float* __restrict__ prj) {
    __shared__ short As[32][264];
    const int t = threadIdx.x;
    const int base = blockIdx.x * 32;

    // ---- stage value rows -> As (issue early; proj overlaps the latency) ----
    const float4* X4 = (const float4*)(X + (long)base * DIMc);
#pragma unroll
    for (int p = 0; p < 4; ++p) {
        const int c = p * 256 + t;
        const int r = c >> 5, kq = (c & 31) * 2;
        const float4 a = X4[r * 64 + kq];
        const float4 b = X4[r * 64 + kq + 1];
        bf16x8 v;
        v[0] = f2bf(a.x); v[1] = f2bf(a.y); v[2] = f2bf(a.z); v[3] = f2bf(a.w);
        v[4] = f2bf(b.x); v[5] = f2bf(b.y); v[6] = f2bf(b.z); v[7] = f2bf(b.w);
        *(bf16x8*)&As[r][kq * 4] = v;
    }

    const int lane = t & 63, w = t >> 6;
    const int lr = lane & 15, lq = lane >> 4;

    // ---- proj (no LDS, no barrier needed) ----
    {
        const int rt = w >> 1, cg = w & 1;
        f32x4 pacc[3];
#pragma unroll
        for (int jj = 0; jj < 3; ++jj) pacc[jj] = (f32x4){0.f, 0.f, 0.f, 0.f};
        const float* Qrow = Q + (long)(base + rt * 16 + lr) * DIMc;
#pragma unroll
        for (int ks = 0; ks < 8; ++ks) {
            const int k0 = ks * 32 + lq * 8;
            const float4 a0 = *(const float4*)(Qrow + k0);
            const float4 a1 = *(const float4*)(Qrow + k0 + 4);
            const float xs[8] = {a0.x, a0.y, a0.z, a0.w, a1.x, a1.y, a1.z, a1.w};
            bf16x8 ah, al;
#pragma unroll
            for (int e = 0; e < 8; ++e) {
                const short hh = f2bf(xs[e]);
                ah[e] = hh;
                al[e] = f2bf(xs[e] - bfbits((unsigned short)hh));
            }
#pragma unroll
            for (int jj = 0; jj < 3; ++jj) {
                const int c = cg * 48 + jj * 16 + lr;
                const bf16x8 bh = *(const bf16x8*)&WpHi[c * 256 + k0];
                const bf16x8 bl = *(const bf16x8*)&WpLo[c * 256 + k0];
                pacc[jj] = __builtin_amdgcn_mfma_f32_16x16x32_bf16(ah, bh, pacc[jj], 0, 0, 0);
                pacc[jj] = __builtin_amdgcn_mfma_f32_16x16x32_bf16(ah, bl, pacc[jj], 0, 0, 0);
                pacc[jj] = __builtin_amdgcn_mfma_f32_16x16x32_bf16(al, bh, pacc[jj], 0, 0, 0);
            }
        }
#pragma unroll
        for (int jj = 0; jj < 3; ++jj) {
            const int col = cg * 48 + jj * 16 + lr;
            const float bb = (col < 64) ? boff[col] : bwt[col - 64];
#pragma unroll
            for (int reg = 0; reg < 4; ++reg) {
                const int row = rt * 16 + lq * 4 + reg;
                prj[(long)(base + row) * 96 + col] = pacc[jj][reg] + bb;
            }
        }
    }
    __syncthreads();

    // ---- value GEMM: acc 2x4, cols w*64.. ----
    f32x4 acc[2][4];
#pragma unroll
    for (int i = 0; i < 2; ++i)
#pragma unroll
        for (int j = 0; j < 4; ++j) acc[i][j] = (f32x4){0.f, 0.f, 0.f, 0.f};

#pragma unroll
    for (int ks = 0; ks < 8; ++ks) {
        const int k0 = ks * 32 + lq * 8;
        bf16x8 a[2], b[4];
#pragma unroll
        for (int i = 0; i < 2; ++i)
            a[i] = *(const bf16x8*)&As[i * 16 + lr][k0];
#pragma unroll
        for (int j = 0; j < 4; ++j)
            b[j] = *(const bf16x8*)&WT[(w * 64 + j * 16 + lr) * 256 + k0];
#pragma unroll
        for (int i = 0; i < 2; ++i)
#pragma unroll
            for (int j = 0; j < 4; ++j)
                acc[i][j] = __builtin_amdgcn_mfma_f32_16x16x32_bf16(a[i], b[j], acc[i][j], 0, 0, 0);
    }

    const int b_ = base / Lq;          // 9216 % 32 == 0
    const int l0 = base % Lq;
#pragma unroll
    for (int i = 0; i < 2; ++i) {
        const int mrow = i * 16 + lq * 4;
#pragma unroll
        for (int j = 0; j < 4; ++j) {
            const int n  = w * 64 + j * 16 + lr;
            const float bb = bias[n];
            const f32x4 v = acc[i][j];
            const int h = n >> 5, d = n & 31;
            __hip_bfloat16* yb = Yv + (((long)(b_ * NHc + h)) * Lq + (l0 + mrow)) * HDc + d;
#pragma unroll
            for (int reg = 0; reg < 4; ++reg)
                yb[(long)reg * HDc] = __float2bfloat16(v[reg] + bb);
        }
    }
}

// Pure gather: prj tile -> records (f16 premult weights) -> ushort8 gather -> bf16 midb.
// 32 rows/block, 256 threads, LDS 24.6KB -> 6 blocks/CU. Grid 1152 = 8*144, XCD-swizzled.
__global__ __launch_bounds__(256, 6) void deform_gather(
        const float* __restrict__ prj,
        const __hip_bfloat16* __restrict__ vws,
        __hip_bfloat16* __restrict__ midb) {
    __shared__ float prjs[32 * 96];      // 12,288 B
    __shared__ int   recI[1024];         //  4,096 B
    __shared__ h16x4 recW[1024];         //  8,192 B

    const int t = threadIdx.x;
    const int bid = (int)blockIdx.x;
    const int lb = (bid & 7) * 144 + (bid >> 3);   // XCD swizzle: each XCD -> one batch
    const int base = lb * 32;
    const int b  = base / Lq;
    const int l0 = base % Lq;

    // ---- stage prj tile (coalesced) ----
    const float4* P4 = (const float4*)(prj + (long)base * 96);
#pragma unroll
    for (int i = 0; i < 3; ++i)
        ((float4*)prjs)[t + 256 * i] = P4[t + 256 * i];
    __syncthreads();

    // ---- records ----
#pragma unroll
    for (int i = 0; i < 4; ++i) {
        const int s = i * 256 + t;
        const int r = s >> 5, u = s & 31;
        const int h = u >> 2, p = u & 3;
        const int l = l0 + r;
        const float* pr = &prjs[r * 96];
        const float inv = 1.0f / (SIDEc - 1);
        const float xr = (float)(l % SIDEc) * inv;
        const float yr = (float)(l / SIDEc) * inv;

        const float4 lg = *(const float4*)&pr[64 + h * 4];
        const float m = fmaxf(fmaxf(lg.x, lg.y), fmaxf(lg.z, lg.w));
        const float e0 = expf(lg.x - m), e1 = expf(lg.y - m);
        const float e2 = expf(lg.z - m), e3 = expf(lg.w - m);
        const float sum = e0 + e1 + e2 + e3;
        const float ep = (p == 0) ? e0 : (p == 1) ? e1 : (p == 2) ? e2 : e3;
        const float wt = ep / sum;

        const float lx = fminf(fmaxf(xr + pr[u * 2 + 0], 0.f), 1.f);  // comp0->rows (ref quirk)
        const float ly = fminf(fmaxf(yr + pr[u * 2 + 1], 0.f), 1.f);
        const float rowf = lx * (float)(SIDEc - 1);
        const float colf = ly * (float)(SIDEc - 1);
        const float r0f = floorf(rowf), c0f = floorf(colf);
        const int r0 = (int)r0f, c0 = (int)c0f;
        const float fr = rowf - r0f, fc = colf - c0f;
        const int drow = (r0 < SIDEc - 1) ? 1 : 0;
        const int dcol = (c0 < SIDEc - 1) ? 1 : 0;
        recI[s] = (r0 * SIDEc + c0) | (drow << 16) | (dcol << 17);
        h16x4 wh;
        wh[0] = (_Float16)(wt * (1.f - fr) * (1.f - fc));
        wh[1] = (_Float16)(wt * (1.f - fr) * fc);
        wh[2] = (_Float16)(wt * fr * (1.f - fc));
        wh[3] = (_Float16)(wt * fr * fc);
        recW[s] = wh;
    }
    __syncthreads();

    // ---- gather: lane owns (h, 8-channel chunk); 4-lane groups read 64B/corner ----
    const int h = (t >> 2) & 7, dq = t & 3;
    const int rhalf = (t >> 5) & 1, wid = t >> 6;
    const __hip_bfloat16* vb = vws + ((long)(b * NHc + h) * Lq) * HDc + dq * 8;
    const int chan = (t & 31) * 8;

#pragma unroll
    for (int pass = 0; pass < 4; ++pass) {
        const int r = pass * 8 + wid * 2 + rhalf;
        float acc[8];
#pragma unroll
        for (int e = 0; e < 8; ++e) acc[e] = 0.f;
#pragma unroll
        for (int p = 0; p < 4; ++p) {
            const int   mt = recI[r * 32 + h * 4 + p];
            const h16x4 wh = recW[r * 32 + h * 4 + p];
            const float w0 = (float)wh[0], w1 = (float)wh[1];
            const float w2 = (float)wh[2], w3 = (float)wh[3];
            const int sl = mt & 0xFFFF;
            const int dr = (mt & 0x10000) ? SIDEc * HDc : 0;
            const int dc = (mt & 0x20000) ? HDc : 0;
            const __hip_bfloat16* pv = vb + (long)sl * HDc;
            const u16x8 u00 = *(const u16x8*)(pv);
            const u16x8 u01 = *(const u16x8*)(pv + dc);
            const u16x8 u10 = *(const u16x8*)(pv + dr);
            const u16x8 u11 = *(const u16x8*)(pv + dr + dc);
#pragma unroll
            for (int e = 0; e < 8; ++e)
                acc[e] += w0 * bfbits(u00[e]) + w1 * bfbits(u01[e])
                        + w2 * bfbits(u10[e]) + w3 * bfbits(u11[e]);
        }
        const int rg = base + r;
        u16x8 o;
#pragma unroll
        for (int e = 0; e < 8; ++e) o[e] = (unsigned short)f2bf(acc[e]);
        // packed into gemm2 block (rg>>5)'s own f32 out region (first half) -> alias-safe
        *(u16x8*)(midb + ((long)(rg >> 5) << 14) + ((rg & 31) << 8) + chan) = o;
    }
}

// gemm2: BM=32, 4 waves, bf16 packed input (per-32-row block at Xb + blk*16384),
// f32 row-major out (same region; staged to LDS + barrier before overwrite).
__global__ __launch_bounds__(256, 4) void gemm2_mfma(
        const short* Xb, const short* __restrict__ WT,
        const float* __restrict__ bias, float* Yo) {
    __shared__ short As[32][264];
    const int t = threadIdx.x;
    const int base = blockIdx.x * 32;

#pragma unroll
    for (int p = 0; p < 4; ++p) {
        const int c = p * 256 + t;
        const int r = c >> 5, k0 = (c & 31) * 8;
        *(bf16x8*)&As[r][k0] = *(const bf16x8*)&Xb[((long)blockIdx.x << 14) + r * 256 + k0];
    }
    __syncthreads();

    const int lane = t & 63, w = t >> 6;
    const int lr = lane & 15, lq = lane >> 4;

    f32x4 acc[2][4];
#pragma unroll
    for (int i = 0; i < 2; ++i)
#pragma unroll
        for (int j = 0; j < 4; ++j) acc[i][j] = (f32x4){0.f, 0.f, 0.f, 0.f};

#pragma unroll
    for (int ks = 0; ks < 8; ++ks) {
        const int k0 = ks * 32 + lq * 8;
        bf16x8 a[2], b[4];
#pragma unroll
        for (int i = 0; i < 2; ++i)
            a[i] = *(const bf16x8*)&As[i * 16 + lr][k0];
#pragma unroll
        for (int j = 0; j < 4; ++j)
            b[j] = *(const bf16x8*)&WT[(w * 64 + j * 16 + lr) * 256 + k0];
#pragma unroll
        for (int i = 0; i < 2; ++i)
#pragma unroll
            for (int j = 0; j < 4; ++j)
                acc[i][j] = __builtin_amdgcn_mfma_f32_16x16x32_bf16(a[i], b[j], acc[i][j], 0, 0, 0);
    }

#pragma unroll
    for (int i = 0; i < 2; ++i) {
        const int mrow = i * 16 + lq * 4;
#pragma unroll
        for (int j = 0; j < 4; ++j) {
            const int n  = w * 64 + j * 16 + lr;
            const float bb = bias[n];
            const f32x4 v = acc[i][j];
            float* yo = Yo + (long)(base + mrow) * DIMc + n;
#pragma unroll
            for (int reg = 0; reg < 4; ++reg)
                yo[(long)reg * DIMc] = v[reg] + bb;
        }
    }
}

extern "C" void kernel_launch(void* const* d_in, const int* in_sizes, int n_in,
                              void* d_out, int out_size, void* d_ws, size_t ws_size,
                              hipStream_t stream) {
    const float* query = (const float*)d_in[0];
    // d_in[1] = key: unused by the reference
    const float* value = (const float*)d_in[2];
    const float* Wv    = (const float*)d_in[3];
    const float* bv    = (const float*)d_in[4];
    const float* Woff  = (const float*)d_in[5];
    const float* boff  = (const float*)d_in[6];
    const float* Wwt   = (const float*)d_in[7];
    const float* bwt   = (const float*)d_in[8];
    const float* Wo    = (const float*)d_in[9];
    const float* bo    = (const float*)d_in[10];

    float* out = (float*)d_out;
    char*  ws  = (char*)d_ws;
    __hip_bfloat16* vws = (__hip_bfloat16*)ws;                       // 18,874,368 B
    short* WvT  = (short*)(ws + 18874368);                           // 131,072 B
    short* WoT  = (short*)(ws + 18874368 + 131072);                  // 131,072 B
    short* WpHi = (short*)(ws + 18874368 + 262144);                  // 49,152 B
    short* WpLo = (short*)(ws + 18874368 + 262144 + 49152);          // 49,152 B
    float* prj  = (float*)(ws + 18874368 + 262144 + 98304);         // 14,155,776 B (tot ~33.4 MB)
    __hip_bfloat16* midb = (__hip_bfloat16*)d_out;                   // packed per 32-row block

    const int nrows = Bq * Lq;   // 36864

    prep<<<160, 256, 0, stream>>>(Wv, Wo, Woff, Wwt, WvT, WoT, WpHi, WpLo);
    gemm1_proj<<<nrows / 32, 256, 0, stream>>>(value, query, WvT, WpHi, WpLo,
                                               bv, boff, bwt, vws, prj);
    deform_gather<<<nrows / 32, 256, 0, stream>>>(prj, vws, midb);
    gemm2_mfma<<<nrows / 32, 256, 0, stream>>>((const short*)midb, WoT, bo, out);
}

// Round 7
// 201.203 us; speedup vs baseline: 1.1083x; 1.1083x over previous
//
#include <hip/hip_runtime.h>
#include <hip/hip_bf16.h>

#define Bq   4
#define Lq   9216
#define DIMc 256
#define NHc  8
#define NPc  4
#define HDc  32
#define SIDEc 96

using f32x4  = __attribute__((ext_vector_type(4))) float;
using bf16x8 = __attribute__((ext_vector_type(8))) short;
using u16x8  = __attribute__((ext_vector_type(8))) unsigned short;
using h16x4  = __attribute__((ext_vector_type(4))) _Float16;

static __device__ __forceinline__ short f2bf(float x) {
    union { __hip_bfloat16 h; short s; } u;
    u.h = __float2bfloat16(x);
    return u.s;
}
static __device__ __forceinline__ float bfbits(unsigned short s) {
    union { unsigned u; float f; } v; v.u = ((unsigned)s) << 16; return v.f;
}

// blocks 0..63: coalesced transpose Wv/Wo -> WT[n][k] bf16 (8 cols/block via LDS).
// blocks 64..159: split-bf16 projection weights WpHi/WpLo [96][256].
__global__ void prep(const float* __restrict__ Wv, const float* __restrict__ Wo,
                     const float* __restrict__ Woff, const float* __restrict__ Wwt,
                     short* __restrict__ WvT, short* __restrict__ WoT,
                     short* __restrict__ WpHi, short* __restrict__ WpLo) {
    const int id = blockIdx.x, t = threadIdx.x;
    if (id < 64) {
        __shared__ float tile[256][8];
        const float* W = (id < 32) ? Wv : Wo;
        short* T = (id < 32) ? WvT : WoT;
        const int n0 = (id & 31) * 8;
        const float4 a = *(const float4*)&W[t * 256 + n0];
        const float4 b = *(const float4*)&W[t * 256 + n0 + 4];
        tile[t][0] = a.x; tile[t][1] = a.y; tile[t][2] = a.z; tile[t][3] = a.w;
        tile[t][4] = b.x; tile[t][5] = b.y; tile[t][6] = b.z; tile[t][7] = b.w;
        __syncthreads();
        const int n = n0 + (t >> 5), kk = (t & 31) * 8;
        bf16x8 v;
#pragma unroll
        for (int e = 0; e < 8; ++e) v[e] = f2bf(tile[kk + e][t >> 5]);
        *(bf16x8*)&T[n * 256 + kk] = v;
    } else {
        const int p = id - 64;       // 0..95
        const float x = (p < 64) ? Woff[t * 64 + p] : Wwt[t * 32 + (p - 64)];
        const short h = f2bf(x);
        WpHi[p * 256 + t] = h;
        WpLo[p * 256 + t] = f2bf(x - bfbits((unsigned short)h));
    }
}

// C[36864x256] = X @ WT^T + bias.  BM=64, 4 waves, wave tile 64x64.
// BF16IN: X bf16 packed per-64-row block at Xb + blk*32768 (first half of that
// block's own f32 output region -> alias-safe after LDS stage + barrier).
// VOUT: bf16 out to [B,NH,L,HD]; else f32 row-major.
template<bool VOUT, bool BF16IN>
__global__ __launch_bounds__(256, 3) void gemm_mfma(
        const float* __restrict__ Xf, const short* Xb,
        const short* __restrict__ WT, const float* __restrict__ bias,
        __hip_bfloat16* __restrict__ Yv, float* Yo) {
    __shared__ short As[64][264];
    const int t = threadIdx.x;
    const int base = blockIdx.x * 64;

    if (BF16IN) {
#pragma unroll
        for (int p = 0; p < 8; ++p) {
            const int c = p * 256 + t;
            const int r = c >> 5, k0 = (c & 31) * 8;
            *(bf16x8*)&As[r][k0] = *(const bf16x8*)&Xb[((long)blockIdx.x << 15) + r * 256 + k0];
        }
    } else {
        const float4* X4 = (const float4*)(Xf + (long)base * DIMc);
#pragma unroll
        for (int p = 0; p < 8; ++p) {
            const int c = p * 256 + t;
            const int r = c >> 5, kq = (c & 31) * 2;
            const float4 a = X4[r * 64 + kq];
            const float4 b = X4[r * 64 + kq + 1];
            bf16x8 v;
            v[0] = f2bf(a.x); v[1] = f2bf(a.y); v[2] = f2bf(a.z); v[3] = f2bf(a.w);
            v[4] = f2bf(b.x); v[5] = f2bf(b.y); v[6] = f2bf(b.z); v[7] = f2bf(b.w);
            *(bf16x8*)&As[r][kq * 4] = v;
        }
    }
    __syncthreads();

    const int lane = t & 63, wc = t >> 6;
    const int lr = lane & 15, lq = lane >> 4;

    f32x4 acc[4][4];
#pragma unroll
    for (int i = 0; i < 4; ++i)
#pragma unroll
        for (int j = 0; j < 4; ++j) acc[i][j] = (f32x4){0.f, 0.f, 0.f, 0.f};

#pragma unroll
    for (int ks = 0; ks < 8; ++ks) {
        const int k0 = ks * 32 + lq * 8;
        bf16x8 a[4], b[4];
#pragma unroll
        for (int i = 0; i < 4; ++i)
            a[i] = *(const bf16x8*)&As[i * 16 + lr][k0];
#pragma unroll
        for (int j = 0; j < 4; ++j)
            b[j] = *(const bf16x8*)&WT[(wc * 64 + j * 16 + lr) * 256 + k0];
#pragma unroll
        for (int i = 0; i < 4; ++i)
#pragma unroll
            for (int j = 0; j < 4; ++j)
                acc[i][j] = __builtin_amdgcn_mfma_f32_16x16x32_bf16(a[i], b[j], acc[i][j], 0, 0, 0);
    }

    const int b_ = base / Lq;          // 9216 % 64 == 0
    const int l0 = base % Lq;
#pragma unroll
    for (int i = 0; i < 4; ++i) {
        const int mrow = i * 16 + lq * 4;
#pragma unroll
        for (int j = 0; j < 4; ++j) {
            const int n  = wc * 64 + j * 16 + lr;
            const float bb = bias[n];
            const f32x4 v = acc[i][j];
            if (VOUT) {
                const int h = n >> 5, d = n & 31;
                __hip_bfloat16* yb = Yv + (((long)(b_ * NHc + h)) * Lq + (l0 + mrow)) * HDc + d;
#pragma unroll
                for (int reg = 0; reg < 4; ++reg)
                    yb[(long)reg * HDc] = __float2bfloat16(v[reg] + bb);
            } else {
                float* yo = Yo + (long)(base + mrow) * DIMc + n;
#pragma unroll
                for (int reg = 0; reg < 4; ++reg)
                    yo[(long)reg * DIMc] = v[reg] + bb;
            }
        }
    }
}

// Fused: split-bf16 MFMA proj (Q read straight from global) -> prjs(LDS) ->
// records (f16 premult weights) -> gather -> bf16 midb.
// 32 rows/block, 4 waves, LDS 24.6KB -> 6 blocks/CU. Grid 1152 = 8*144, XCD-swizzled.
// Keeping proj in-kernel meters the gather request rate (R6 showed a pure-gather
// kernel at high occupancy thrashes L2: FETCH 43->211 MB).
__global__ __launch_bounds__(256, 6) void deform_fused3(
        const float* __restrict__ Q,
        const short* __restrict__ WpHi, const short* __restrict__ WpLo,
        const float* __restrict__ boff, const float* __restrict__ bwt,
        const __hip_bfloat16* __restrict__ vws,
        __hip_bfloat16* __restrict__ midb) {
    __shared__ float prjs[32 * 96];      // 12,288 B
    __shared__ int   recI[1024];         //  4,096 B
    __shared__ h16x4 recW[1024];         //  8,192 B  (total 24,576 B)

    const int t = threadIdx.x;
    const int bid = (int)blockIdx.x;
    const int lb = (bid & 7) * 144 + (bid >> 3);   // XCD swizzle: each XCD -> one batch half
    const int base = lb * 32;
    const int b  = base / Lq;
    const int l0 = base % Lq;

    const int lane = t & 63, w = t >> 6;
    const int lr = lane & 15, lq = lane >> 4;

    // ---- proj: wave w -> rows (w>>1)*16, cols (w&1)*48; A-frags from global Q ----
    {
        const int rt = w >> 1, cg = w & 1;
        f32x4 pacc[3];
#pragma unroll
        for (int jj = 0; jj < 3; ++jj) pacc[jj] = (f32x4){0.f, 0.f, 0.f, 0.f};
        const float* Qrow = Q + (long)(base + rt * 16 + lr) * DIMc;
#pragma unroll
        for (int ks = 0; ks < 8; ++ks) {
            const int k0 = ks * 32 + lq * 8;
            const float4 a0 = *(const float4*)(Qrow + k0);
            const float4 a1 = *(const float4*)(Qrow + k0 + 4);
            const float xs[8] = {a0.x, a0.y, a0.z, a0.w, a1.x, a1.y, a1.z, a1.w};
            bf16x8 ah, al;
#pragma unroll
            for (int e = 0; e < 8; ++e) {
                const short hh = f2bf(xs[e]);
                ah[e] = hh;
                al[e] = f2bf(xs[e] - bfbits((unsigned short)hh));
            }
#pragma unroll
            for (int jj = 0; jj < 3; ++jj) {
                const int c = cg * 48 + jj * 16 + lr;
                const bf16x8 bh = *(const bf16x8*)&WpHi[c * 256 + k0];
                const bf16x8 bl = *(const bf16x8*)&WpLo[c * 256 + k0];
                pacc[jj] = __builtin_amdgcn_mfma_f32_16x16x32_bf16(ah, bh, pacc[jj], 0, 0, 0);
                pacc[jj] = __builtin_amdgcn_mfma_f32_16x16x32_bf16(ah, bl, pacc[jj], 0, 0, 0);
                pacc[jj] = __builtin_amdgcn_mfma_f32_16x16x32_bf16(al, bh, pacc[jj], 0, 0, 0);
            }
        }
#pragma unroll
        for (int jj = 0; jj < 3; ++jj) {
            const int col = cg * 48 + jj * 16 + lr;
            const float bb = (col < 64) ? boff[col] : bwt[col - 64];
#pragma unroll
            for (int reg = 0; reg < 4; ++reg) {
                const int row = rt * 16 + lq * 4 + reg;
                prjs[row * 96 + col] = pacc[jj][reg] + bb;
            }
        }
    }
    __syncthreads();

    // ---- records: softmax wt premultiplied bilinear weights (f16 packed) ----
#pragma unroll
    for (int i = 0; i < 4; ++i) {
        const int s = i * 256 + t;
        const int r = s >> 5, u = s & 31;
        const int h = u >> 2, p = u & 3;
        const int l = l0 + r;
        const float* pr = &prjs[r * 96];
        const float inv = 1.0f / (SIDEc - 1);
        const float xr = (float)(l % SIDEc) * inv;
        const float yr = (float)(l / SIDEc) * inv;

        const float4 lg = *(const float4*)&pr[64 + h * 4];
        const float m = fmaxf(fmaxf(lg.x, lg.y), fmaxf(lg.z, lg.w));
        const float e0 = expf(lg.x - m), e1 = expf(lg.y - m);
        const float e2 = expf(lg.z - m), e3 = expf(lg.w - m);
        const float sum = e0 + e1 + e2 + e3;
        const float ep = (p == 0) ? e0 : (p == 1) ? e1 : (p == 2) ? e2 : e3;
        const float wt = ep / sum;

        const float lx = fminf(fmaxf(xr + pr[u * 2 + 0], 0.f), 1.f);  // comp0->rows (ref quirk)
        const float ly = fminf(fmaxf(yr + pr[u * 2 + 1], 0.f), 1.f);
        const float rowf = lx * (float)(SIDEc - 1);
        const float colf = ly * (float)(SIDEc - 1);
        const float r0f = floorf(rowf), c0f = floorf(colf);
        const int r0 = (int)r0f, c0 = (int)c0f;
        const float fr = rowf - r0f, fc = colf - c0f;
        const int drow = (r0 < SIDEc - 1) ? 1 : 0;
        const int dcol = (c0 < SIDEc - 1) ? 1 : 0;
        recI[s] = (r0 * SIDEc + c0) | (drow << 16) | (dcol << 17);
        h16x4 wh;
        wh[0] = (_Float16)(wt * (1.f - fr) * (1.f - fc));
        wh[1] = (_Float16)(wt * (1.f - fr) * fc);
        wh[2] = (_Float16)(wt * fr * (1.f - fc));
        wh[3] = (_Float16)(wt * fr * fc);
        recW[s] = wh;
    }
    __syncthreads();

    // ---- gather: lane owns (h, 8-channel chunk); 4-lane groups read 64B/corner ----
    const int h = (t >> 2) & 7, dq = t & 3;
    const int rhalf = (t >> 5) & 1, wid = t >> 6;
    const __hip_bfloat16* vb = vws + ((long)(b * NHc + h) * Lq) * HDc + dq * 8;
    const int chan = (t & 31) * 8;

#pragma unroll
    for (int pass = 0; pass < 4; ++pass) {
        const int r = pass * 8 + wid * 2 + rhalf;
        float acc[8];
#pragma unroll
        for (int e = 0; e < 8; ++e) acc[e] = 0.f;
#pragma unroll
        for (int p = 0; p < 4; ++p) {
            const int   mt = recI[r * 32 + h * 4 + p];
            const h16x4 wh = recW[r * 32 + h * 4 + p];
            const float w0 = (float)wh[0], w1 = (float)wh[1];
            const float w2 = (float)wh[2], w3 = (float)wh[3];
            const int sl = mt & 0xFFFF;
            const int dr = (mt & 0x10000) ? SIDEc * HDc : 0;
            const int dc = (mt & 0x20000) ? HDc : 0;
            const __hip_bfloat16* pv = vb + (long)sl * HDc;
            const u16x8 u00 = *(const u16x8*)(pv);
            const u16x8 u01 = *(const u16x8*)(pv + dc);
            const u16x8 u10 = *(const u16x8*)(pv + dr);
            const u16x8 u11 = *(const u16x8*)(pv + dr + dc);
#pragma unroll
            for (int e = 0; e < 8; ++e)
                acc[e] += w0 * bfbits(u00[e]) + w1 * bfbits(u01[e])
                        + w2 * bfbits(u10[e]) + w3 * bfbits(u11[e]);
        }
        const int rg = base + r;
        u16x8 o;
#pragma unroll
        for (int e = 0; e < 8; ++e) o[e] = (unsigned short)f2bf(acc[e]);
        // packed into gemm2 block (rg>>6)'s own f32 out region (first half) -> alias-safe
        *(u16x8*)(midb + ((long)(rg >> 6) << 15) + ((rg & 63) << 8) + chan) = o;
    }
}

extern "C" void kernel_launch(void* const* d_in, const int* in_sizes, int n_in,
                              void* d_out, int out_size, void* d_ws, size_t ws_size,
                              hipStream_t stream) {
    const float* query = (const float*)d_in[0];
    // d_in[1] = key: unused by the reference
    const float* value = (const float*)d_in[2];
    const float* Wv    = (const float*)d_in[3];
    const float* bv    = (const float*)d_in[4];
    const float* Woff  = (const float*)d_in[5];
    const float* boff  = (const float*)d_in[6];
    const float* Wwt   = (const float*)d_in[7];
    const float* bwt   = (const float*)d_in[8];
    const float* Wo    = (const float*)d_in[9];
    const float* bo    = (const float*)d_in[10];

    float* out = (float*)d_out;
    char*  ws  = (char*)d_ws;
    __hip_bfloat16* vws = (__hip_bfloat16*)ws;                       // 18,874,368 B
    short* WvT  = (short*)(ws + 18874368);                           // 131,072 B
    short* WoT  = (short*)(ws + 18874368 + 131072);                  // 131,072 B
    short* WpHi = (short*)(ws + 18874368 + 262144);                  // 49,152 B
    short* WpLo = (short*)(ws + 18874368 + 262144 + 49152);          // 49,152 B
    __hip_bfloat16* midb = (__hip_bfloat16*)d_out;                   // packed per 64-row block

    const int nrows = Bq * Lq;   // 36864

    prep<<<160, 256, 0, stream>>>(Wv, Wo, Woff, Wwt, WvT, WoT, WpHi, WpLo);
    gemm_mfma<true, false><<<nrows / 64, 256, 0, stream>>>(value, nullptr, WvT, bv, vws, nullptr);
    deform_fused3<<<nrows / 32, 256, 0, stream>>>(query, WpHi, WpLo, boff, bwt, vws, midb);
    gemm_mfma<false, true><<<nrows / 64, 256, 0, stream>>>(nullptr, (const short*)midb, WoT, bo, nullptr, out);
}

// Round 8
// 104.822 us; speedup vs baseline: 2.1274x; 1.9195x over previous
//
#include <hip/hip_runtime.h>
#include <hip/hip_bf16.h>

#define Bq   4
#define Lq   9216
#define DIMc 256
#define NHc  8
#define NPc  4
#define HDc  32
#define SIDEc 96

using f32x4  = __attribute__((ext_vector_type(4))) float;
using bf16x8 = __attribute__((ext_vector_type(8))) short;
using u16x8  = __attribute__((ext_vector_type(8))) unsigned short;
using h16x4  = __attribute__((ext_vector_type(4))) _Float16;

static __device__ __forceinline__ short f2bf(float x) {
    union { __hip_bfloat16 h; short s; } u;
    u.h = __float2bfloat16(x);
    return u.s;
}
static __device__ __forceinline__ float bfbits(unsigned short s) {
    union { unsigned u; float f; } v; v.u = ((unsigned)s) << 16; return v.f;
}

// blocks 0..63: coalesced transpose Wv/Wo -> WT[n][k] bf16 (8 cols/block via LDS).
// blocks 64..159: split-bf16 projection weights WpHi/WpLo [96][256].
__global__ void prep(const float* __restrict__ Wv, const float* __restrict__ Wo,
                     const float* __restrict__ Woff, const float* __restrict__ Wwt,
                     short* __restrict__ WvT, short* __restrict__ WoT,
                     short* __restrict__ WpHi, short* __restrict__ WpLo) {
    const int id = blockIdx.x, t = threadIdx.x;
    if (id < 64) {
        __shared__ float tile[256][8];
        const float* W = (id < 32) ? Wv : Wo;
        short* T = (id < 32) ? WvT : WoT;
        const int n0 = (id & 31) * 8;
        const float4 a = *(const float4*)&W[t * 256 + n0];
        const float4 b = *(const float4*)&W[t * 256 + n0 + 4];
        tile[t][0] = a.x; tile[t][1] = a.y; tile[t][2] = a.z; tile[t][3] = a.w;
        tile[t][4] = b.x; tile[t][5] = b.y; tile[t][6] = b.z; tile[t][7] = b.w;
        __syncthreads();
        const int n = n0 + (t >> 5), kk = (t & 31) * 8;
        bf16x8 v;
#pragma unroll
        for (int e = 0; e < 8; ++e) v[e] = f2bf(tile[kk + e][t >> 5]);
        *(bf16x8*)&T[n * 256 + kk] = v;
    } else {
        const int p = id - 64;       // 0..95
        const float x = (p < 64) ? Woff[t * 64 + p] : Wwt[t * 32 + (p - 64)];
        const short h = f2bf(x);
        WpHi[p * 256 + t] = h;
        WpLo[p * 256 + t] = f2bf(x - bfbits((unsigned short)h));
    }
}

// C[36864x256] = X @ WT^T + bias.  BM=64, 4 waves, wave tile 64x64.
// BF16IN: X bf16 packed per-64-row block at Xb + blk*32768 (first half of that
// block's own f32 output region -> alias-safe after LDS stage + barrier).
// VOUT: bf16 out to [B,NH,L,HD]; else f32 row-major.
template<bool VOUT, bool BF16IN>
__global__ __launch_bounds__(256, 3) void gemm_mfma(
        const float* __restrict__ Xf, const short* Xb,
        const short* __restrict__ WT, const float* __restrict__ bias,
        __hip_bfloat16* __restrict__ Yv, float* Yo) {
    __shared__ short As[64][264];
    const int t = threadIdx.x;
    const int base = blockIdx.x * 64;

    if (BF16IN) {
#pragma unroll
        for (int p = 0; p < 8; ++p) {
            const int c = p * 256 + t;
            const int r = c >> 5, k0 = (c & 31) * 8;
            *(bf16x8*)&As[r][k0] = *(const bf16x8*)&Xb[((long)blockIdx.x << 15) + r * 256 + k0];
        }
    } else {
        const float4* X4 = (const float4*)(Xf + (long)base * DIMc);
#pragma unroll
        for (int p = 0; p < 8; ++p) {
            const int c = p * 256 + t;
            const int r = c >> 5, kq = (c & 31) * 2;
            const float4 a = X4[r * 64 + kq];
            const float4 b = X4[r * 64 + kq + 1];
            bf16x8 v;
            v[0] = f2bf(a.x); v[1] = f2bf(a.y); v[2] = f2bf(a.z); v[3] = f2bf(a.w);
            v[4] = f2bf(b.x); v[5] = f2bf(b.y); v[6] = f2bf(b.z); v[7] = f2bf(b.w);
            *(bf16x8*)&As[r][kq * 4] = v;
        }
    }
    __syncthreads();

    const int lane = t & 63, wc = t >> 6;
    const int lr = lane & 15, lq = lane >> 4;

    f32x4 acc[4][4];
#pragma unroll
    for (int i = 0; i < 4; ++i)
#pragma unroll
        for (int j = 0; j < 4; ++j) acc[i][j] = (f32x4){0.f, 0.f, 0.f, 0.f};

#pragma unroll
    for (int ks = 0; ks < 8; ++ks) {
        const int k0 = ks * 32 + lq * 8;
        bf16x8 a[4], b[4];
#pragma unroll
        for (int i = 0; i < 4; ++i)
            a[i] = *(const bf16x8*)&As[i * 16 + lr][k0];
#pragma unroll
        for (int j = 0; j < 4; ++j)
            b[j] = *(const bf16x8*)&WT[(wc * 64 + j * 16 + lr) * 256 + k0];
#pragma unroll
        for (int i = 0; i < 4; ++i)
#pragma unroll
            for (int j = 0; j < 4; ++j)
                acc[i][j] = __builtin_amdgcn_mfma_f32_16x16x32_bf16(a[i], b[j], acc[i][j], 0, 0, 0);
    }

    const int b_ = base / Lq;          // 9216 % 64 == 0
    const int l0 = base % Lq;
#pragma unroll
    for (int i = 0; i < 4; ++i) {
        const int mrow = i * 16 + lq * 4;
#pragma unroll
        for (int j = 0; j < 4; ++j) {
            const int n  = wc * 64 + j * 16 + lr;
            const float bb = bias[n];
            const f32x4 v = acc[i][j];
            if (VOUT) {
                const int h = n >> 5, d = n & 31;
                __hip_bfloat16* yb = Yv + (((long)(b_ * NHc + h)) * Lq + (l0 + mrow)) * HDc + d;
#pragma unroll
                for (int reg = 0; reg < 4; ++reg)
                    yb[(long)reg * HDc] = __float2bfloat16(v[reg] + bb);
            } else {
                float* yo = Yo + (long)(base + mrow) * DIMc + n;
#pragma unroll
                for (int reg = 0; reg < 4; ++reg)
                    yo[(long)reg * DIMc] = v[reg] + bb;
            }
        }
    }
}

// Fused: split-bf16 MFMA proj (Q read straight from global) -> prjs(LDS) ->
// records (f16 premult weights) -> gather -> bf16 midb.
// 32 rows/block, 4 waves, LDS 24.6KB. Grid 1152 = 8*144, XCD-swizzled.
// launch_bounds(256,3): R6/R7's (256,6) forced VGPR=40 -> scratch spills
// (WRITE_SIZE 256MB vs 19MB algorithmic). Cap at 3 waves/EU -> no spill.
__global__ __launch_bounds__(256, 3) void deform_fused3(
        const float* __restrict__ Q,
        const short* __restrict__ WpHi, const short* __restrict__ WpLo,
        const float* __restrict__ boff, const float* __restrict__ bwt,
        const __hip_bfloat16* __restrict__ vws,
        __hip_bfloat16* __restrict__ midb) {
    __shared__ float prjs[32 * 96];      // 12,288 B
    __shared__ int   recI[1024];         //  4,096 B
    __shared__ h16x4 recW[1024];         //  8,192 B  (total 24,576 B)

    const int t = threadIdx.x;
    const int bid = (int)blockIdx.x;
    const int lb = (bid & 7) * 144 + (bid >> 3);   // XCD swizzle: each XCD -> one batch half
    const int base = lb * 32;
    const int b  = base / Lq;
    const int l0 = base % Lq;

    const int lane = t & 63, w = t >> 6;
    const int lr = lane & 15, lq = lane >> 4;

    // ---- proj: wave w -> rows (w>>1)*16, cols (w&1)*48; A-frags from global Q ----
    {
        const int rt = w >> 1, cg = w & 1;
        f32x4 pacc[3];
#pragma unroll
        for (int jj = 0; jj < 3; ++jj) pacc[jj] = (f32x4){0.f, 0.f, 0.f, 0.f};
        const float* Qrow = Q + (long)(base + rt * 16 + lr) * DIMc;
#pragma unroll
        for (int ks = 0; ks < 8; ++ks) {
            const int k0 = ks * 32 + lq * 8;
            const float4 a0 = *(const float4*)(Qrow + k0);
            const float4 a1 = *(const float4*)(Qrow + k0 + 4);
            const float xs[8] = {a0.x, a0.y, a0.z, a0.w, a1.x, a1.y, a1.z, a1.w};
            bf16x8 ah, al;
#pragma unroll
            for (int e = 0; e < 8; ++e) {
                const short hh = f2bf(xs[e]);
                ah[e] = hh;
                al[e] = f2bf(xs[e] - bfbits((unsigned short)hh));
            }
#pragma unroll
            for (int jj = 0; jj < 3; ++jj) {
                const int c = cg * 48 + jj * 16 + lr;
                const bf16x8 bh = *(const bf16x8*)&WpHi[c * 256 + k0];
                const bf16x8 bl = *(const bf16x8*)&WpLo[c * 256 + k0];
                pacc[jj] = __builtin_amdgcn_mfma_f32_16x16x32_bf16(ah, bh, pacc[jj], 0, 0, 0);
                pacc[jj] = __builtin_amdgcn_mfma_f32_16x16x32_bf16(ah, bl, pacc[jj], 0, 0, 0);
                pacc[jj] = __builtin_amdgcn_mfma_f32_16x16x32_bf16(al, bh, pacc[jj], 0, 0, 0);
            }
        }
#pragma unroll
        for (int jj = 0; jj < 3; ++jj) {
            const int col = cg * 48 + jj * 16 + lr;
            const float bb = (col < 64) ? boff[col] : bwt[col - 64];
#pragma unroll
            for (int reg = 0; reg < 4; ++reg) {
                const int row = rt * 16 + lq * 4 + reg;
                prjs[row * 96 + col] = pacc[jj][reg] + bb;
            }
        }
    }
    __syncthreads();

    // ---- records: softmax wt premultiplied bilinear weights (f16 packed) ----
#pragma unroll
    for (int i = 0; i < 4; ++i) {
        const int s = i * 256 + t;
        const int r = s >> 5, u = s & 31;
        const int h = u >> 2, p = u & 3;
        const int l = l0 + r;
        const float* pr = &prjs[r * 96];
        const float inv = 1.0f / (SIDEc - 1);
        const float xr = (float)(l % SIDEc) * inv;
        const float yr = (float)(l / SIDEc) * inv;

        const float4 lg = *(const float4*)&pr[64 + h * 4];
        const float m = fmaxf(fmaxf(lg.x, lg.y), fmaxf(lg.z, lg.w));
        const float e0 = expf(lg.x - m), e1 = expf(lg.y - m);
        const float e2 = expf(lg.z - m), e3 = expf(lg.w - m);
        const float sum = e0 + e1 + e2 + e3;
        const float ep = (p == 0) ? e0 : (p == 1) ? e1 : (p == 2) ? e2 : e3;
        const float wt = ep / sum;

        const float lx = fminf(fmaxf(xr + pr[u * 2 + 0], 0.f), 1.f);  // comp0->rows (ref quirk)
        const float ly = fminf(fmaxf(yr + pr[u * 2 + 1], 0.f), 1.f);
        const float rowf = lx * (float)(SIDEc - 1);
        const float colf = ly * (float)(SIDEc - 1);
        const float r0f = floorf(rowf), c0f = floorf(colf);
        const int r0 = (int)r0f, c0 = (int)c0f;
        const float fr = rowf - r0f, fc = colf - c0f;
        const int drow = (r0 < SIDEc - 1) ? 1 : 0;
        const int dcol = (c0 < SIDEc - 1) ? 1 : 0;
        recI[s] = (r0 * SIDEc + c0) | (drow << 16) | (dcol << 17);
        h16x4 wh;
        wh[0] = (_Float16)(wt * (1.f - fr) * (1.f - fc));
        wh[1] = (_Float16)(wt * (1.f - fr) * fc);
        wh[2] = (_Float16)(wt * fr * (1.f - fc));
        wh[3] = (_Float16)(wt * fr * fc);
        recW[s] = wh;
    }
    __syncthreads();

    // ---- gather: lane owns (h, 8-channel chunk); 4-lane groups read 64B/corner ----
    const int h = (t >> 2) & 7, dq = t & 3;
    const int rhalf = (t >> 5) & 1, wid = t >> 6;
    const __hip_bfloat16* vb = vws + ((long)(b * NHc + h) * Lq) * HDc + dq * 8;
    const int chan = (t & 31) * 8;

#pragma unroll
    for (int pass = 0; pass < 4; ++pass) {
        const int r = pass * 8 + wid * 2 + rhalf;
        float acc[8];
#pragma unroll
        for (int e = 0; e < 8; ++e) acc[e] = 0.f;
#pragma unroll
        for (int p = 0; p < 4; ++p) {
            const int   mt = recI[r * 32 + h * 4 + p];
            const h16x4 wh = recW[r * 32 + h * 4 + p];
            const float w0 = (float)wh[0], w1 = (float)wh[1];
            const float w2 = (float)wh[2], w3 = (float)wh[3];
            const int sl = mt & 0xFFFF;
            const int dr = (mt & 0x10000) ? SIDEc * HDc : 0;
            const int dc = (mt & 0x20000) ? HDc : 0;
            const __hip_bfloat16* pv = vb + (long)sl * HDc;
            const u16x8 u00 = *(const u16x8*)(pv);
            const u16x8 u01 = *(const u16x8*)(pv + dc);
            const u16x8 u10 = *(const u16x8*)(pv + dr);
            const u16x8 u11 = *(const u16x8*)(pv + dr + dc);
#pragma unroll
            for (int e = 0; e < 8; ++e)
                acc[e] += w0 * bfbits(u00[e]) + w1 * bfbits(u01[e])
                        + w2 * bfbits(u10[e]) + w3 * bfbits(u11[e]);
        }
        const int rg = base + r;
        u16x8 o;
#pragma unroll
        for (int e = 0; e < 8; ++e) o[e] = (unsigned short)f2bf(acc[e]);
        // packed into gemm2 block (rg>>6)'s own f32 out region (first half) -> alias-safe
        *(u16x8*)(midb + ((long)(rg >> 6) << 15) + ((rg & 63) << 8) + chan) = o;
    }
}

extern "C" void kernel_launch(void* const* d_in, const int* in_sizes, int n_in,
                              void* d_out, int out_size, void* d_ws, size_t ws_size,
                              hipStream_t stream) {
    const float* query = (const float*)d_in[0];
    // d_in[1] = key: unused by the reference
    const float* value = (const float*)d_in[2];
    const float* Wv    = (const float*)d_in[3];
    const float* bv    = (const float*)d_in[4];
    const float* Woff  = (const float*)d_in[5];
    const float* boff  = (const float*)d_in[6];
    const float* Wwt   = (const float*)d_in[7];
    const float* bwt   = (const float*)d_in[8];
    const float* Wo    = (const float*)d_in[9];
    const float* bo    = (const float*)d_in[10];

    float* out = (float*)d_out;
    char*  ws  = (char*)d_ws;
    __hip_bfloat16* vws = (__hip_bfloat16*)ws;                       // 18,874,368 B
    short* WvT  = (short*)(ws + 18874368);                           // 131,072 B
    short* WoT  = (short*)(ws + 18874368 + 131072);                  // 131,072 B
    short* WpHi = (short*)(ws + 18874368 + 262144);                  // 49,152 B
    short* WpLo = (short*)(ws + 18874368 + 262144 + 49152);          // 49,152 B
    __hip_bfloat16* midb = (__hip_bfloat16*)d_out;                   // packed per 64-row block

    const int nrows = Bq * Lq;   // 36864

    prep<<<160, 256, 0, stream>>>(Wv, Wo, Woff, Wwt, WvT, WoT, WpHi, WpLo);
    gemm_mfma<true, false><<<nrows / 64, 256, 0, stream>>>(value, nullptr, WvT, bv, vws, nullptr);
    deform_fused3<<<nrows / 32, 256, 0, stream>>>(query, WpHi, WpLo, boff, bwt, vws, midb);
    gemm_mfma<false, true><<<nrows / 64, 256, 0, stream>>>(nullptr, (const short*)midb, WoT, bo, nullptr, out);
}